// Round 8
// baseline (124.508 us; speedup 1.0000x reference)
//
#include <hip/hip_runtime.h>
#include <math.h>

#define NN 4096
#define DD 512
#define MARGINF 1.0f
#define NCLS 64
#define MAXM 160
#define TRI (MAXM * (MAXM - 1) / 2)   // 12720
#define NBLK 528                      // 32*33/2 triangular 128-tiles

typedef __attribute__((ext_vector_type(8))) short bf16x8;  // 8 bf16 (4 VGPRs)
typedef __attribute__((ext_vector_type(4))) float f32x4;   // 4 fp32 acc

// ws layout (float indices):
#define WS_SQ   0         // float[4096] ||x_i||^2
#define WS_NS   4096      // float[4096] neg_sum
#define WS_LOSS 8192      // float[1] sum hinge^2
#define WS_CTR  8193      // uint[1] pair2 completion counter
#define WS_CNT  8256      // int[64] class counts
#define WS_RK   8320      // int[4096] rank within class
#define WS_MEM  12416     // int[64*160] class member lists
#define WS_XF   32768     // ushort[4096*512] FRAGMENT-MAJOR bf16 X (4 MB)
                          //   Xf[((r16*16 + kb)*64 + lane)*8 + j]
                          //   r16=row>>4, kb=k>>5, lane=(k>>3&3)*16+(row&15), j=k&7
#define WS_PD   1081344   // float[64*TRI] positive-pair distances

__device__ __forceinline__ unsigned short f2bf(float f) {
    unsigned u = __float_as_uint(f);
    u += 0x7fffu + ((u >> 16) & 1u);   // round-to-nearest-even
    return (unsigned short)(u >> 16);
}

// Row norms + fragment-major bf16 conversion + zero-init. One wave per row.
// Lane covers k = lane*8 .. lane*8+7  (kb = lane>>2, q = lane&3).
__global__ __launch_bounds__(256) void prep_kernel(const float* __restrict__ X,
                                                   float* __restrict__ ws) {
    const int wv = threadIdx.x >> 6, lane = threadIdx.x & 63;
    const int row = blockIdx.x * 4 + wv;
    const float4* xr = (const float4*)(X + (size_t)row * DD);
    float4 a = xr[2 * lane], b = xr[2 * lane + 1];   // floats 8*lane .. 8*lane+7
    float s = a.x * a.x + a.y * a.y + a.z * a.z + a.w * a.w
            + b.x * b.x + b.y * b.y + b.z * b.z + b.w * b.w;
#pragma unroll
    for (int off = 32; off; off >>= 1) s += __shfl_down(s, off, 64);
    if (lane == 0) { ws[WS_SQ + row] = s; ws[WS_NS + row] = 0.0f; }
    ushort4 pa = {f2bf(a.x), f2bf(a.y), f2bf(a.z), f2bf(a.w)};
    ushort4 pb = {f2bf(b.x), f2bf(b.y), f2bf(b.z), f2bf(b.w)};
    const int r16 = row >> 4, m = row & 15;
    const int kb = lane >> 2, q = lane & 3;
    ushort4* dst = (ushort4*)((unsigned short*)(ws + WS_XF)
                              + ((size_t)(r16 * 16 + kb) * 64 + q * 16 + m) * 8);
    dst[0] = pa;
    dst[1] = pb;
    if (blockIdx.x == 0) {
        if (threadIdx.x < NCLS) ((int*)(ws + WS_CNT))[threadIdx.x] = 0;
        if (threadIdx.x == 0) { ws[WS_LOSS] = 0.0f; ((unsigned*)ws)[WS_CTR] = 0u; }
    }
}

__global__ __launch_bounds__(256) void class_build_kernel(const int* __restrict__ tgt,
                                                          float* __restrict__ ws) {
    const int t = blockIdx.x * 256 + threadIdx.x;
    const int c = tgt[t];
    int p = atomicAdd(&((int*)(ws + WS_CNT))[c], 1);
    ((int*)(ws + WS_RK))[t] = p;
    if (p < MAXM) ((int*)(ws + WS_MEM))[c * MAXM + p] = t;
}

// Gram via bf16 MFMA with PRE-SWIZZLED fragment-major operands: every
// fragment load is one wave-coalesced 1KB global_load_dwordx4 (lane*16B
// consecutive). No LDS, no barriers, no bank conflicts. 128x128 tile per
// block (4 waves x 64x64), triangular grid, depth-1 register prefetch.
__global__ __launch_bounds__(256, 3) void negsum_kernel(const int* __restrict__ tgt,
                                                        float* __restrict__ ws) {
    const int bidx = blockIdx.x;
    int bj = (int)((sqrtf(8.0f * (float)bidx + 1.0f) - 1.0f) * 0.5f);
    while (bj * (bj + 1) / 2 > bidx) --bj;
    while ((bj + 1) * (bj + 2) / 2 <= bidx) ++bj;
    const int bi = bidx - bj * (bj + 1) / 2;   // bi <= bj
    const int i0 = bi * 128, j0 = bj * 128;

    const int tid = threadIdx.x;
    const int w = tid >> 6, lane = tid & 63;
    const int m_ = lane & 15, q = lane >> 4;
    const int wr = (w & 1) * 64, wc = (w >> 1) * 64;
    const unsigned short* Xf = (const unsigned short*)(ws + WS_XF);

    // fragment base for row-block rb, k-block it: Xf + (rb*16 + it)*512 + lane*8
    const int air = (i0 + wr) >> 4;   // A row-blocks air..air+3
    const int bjr = (j0 + wc) >> 4;   // B row-blocks bjr..bjr+3
    const unsigned short* pA = Xf + (size_t)air * 16 * 512 + lane * 8;
    const unsigned short* pB = Xf + (size_t)bjr * 16 * 512 + lane * 8;

    f32x4 acc[4][4] = {};
    bf16x8 af[4], bfr[4], nA[4], nB[4];
#pragma unroll
    for (int u = 0; u < 4; ++u) {
        af[u]  = *(const bf16x8*)(pA + (size_t)u * 16 * 512);
        bfr[u] = *(const bf16x8*)(pB + (size_t)u * 16 * 512);
    }
#pragma unroll
    for (int it = 0; it < 16; ++it) {
        if (it < 15) {
#pragma unroll
            for (int u = 0; u < 4; ++u) {
                nA[u] = *(const bf16x8*)(pA + (size_t)u * 16 * 512 + (it + 1) * 512);
                nB[u] = *(const bf16x8*)(pB + (size_t)u * 16 * 512 + (it + 1) * 512);
            }
        }
#pragma unroll
        for (int u = 0; u < 4; ++u)
#pragma unroll
            for (int v = 0; v < 4; ++v)
                acc[u][v] = __builtin_amdgcn_mfma_f32_16x16x32_bf16(
                    af[u], bfr[v], acc[u][v], 0, 0, 0);
#pragma unroll
        for (int u = 0; u < 4; ++u) { af[u] = nA[u]; bfr[u] = nB[u]; }
    }

    // epilogue: C/D map col=lane&15, row=(lane>>4)*4+reg
    const float* sq = ws + WS_SQ;
    float* ns = ws + WS_NS;
    const int* rk = (const int*)(ws + WS_RK);
    float* posd = ws + WS_PD;
    float sjv[4]; int tjv[4], jv[4];
#pragma unroll
    for (int v = 0; v < 4; ++v) {
        int j = j0 + wc + v * 16 + m_;
        jv[v] = j;
        sjv[v] = sq[j];
        tjv[v] = tgt[j];
    }
    float colp[4] = {0.0f, 0.0f, 0.0f, 0.0f};
#pragma unroll
    for (int u = 0; u < 4; ++u) {
#pragma unroll
        for (int r = 0; r < 4; ++r) {
            const int i = i0 + wr + u * 16 + q * 4 + r;
            const float si = sq[i];
            const int ti = tgt[i];
            float rp = 0.0f;
#pragma unroll
            for (int v = 0; v < 4; ++v) {
                float d2 = si + sjv[v] - 2.0f * acc[u][v][r];
                float dist = d2 > 0.0f ? sqrtf(d2) : 0.0f;
                if (tjv[v] != ti) {
                    float e = __expf(MARGINF - dist);
                    rp += e;
                    colp[v] += e;
                } else if (i < jv[v]) {
                    int ra = rk[i], rb = rk[jv[v]];
                    if (ra < MAXM && rb < MAXM) {
                        int hi = ra > rb ? ra : rb;
                        int lo = ra > rb ? rb : ra;
                        posd[ti * TRI + hi * (hi - 1) / 2 + lo] = dist;
                    }
                }
            }
            rp += __shfl_xor(rp, 1, 64);
            rp += __shfl_xor(rp, 2, 64);
            rp += __shfl_xor(rp, 4, 64);
            rp += __shfl_xor(rp, 8, 64);
            if (m_ == 0) atomicAdd(&ns[i], rp);
        }
    }
    if (bi != bj) {   // symmetric contribution: G[j][i] == G[i][j]
#pragma unroll
        for (int v = 0; v < 4; ++v) {
            float cp = colp[v];
            cp += __shfl_xor(cp, 16, 64);
            cp += __shfl_xor(cp, 32, 64);
            if (q == 0) atomicAdd(&ns[jv[v]], cp);
        }
    }
}

// Positive pairs from stored distances; last block computes the final mean.
__global__ __launch_bounds__(256) void pair2_kernel(float* __restrict__ ws,
                                                    float* __restrict__ out) {
    __shared__ float wsum[4];
    __shared__ bool last;
    const int c = blockIdx.x;
    const int tid = threadIdx.x;
    int mc = ((const int*)(ws + WS_CNT))[c];
    if (mc > MAXM) mc = MAXM;
    const int P = mc * (mc - 1) / 2;
    const int* mem = (const int*)(ws + WS_MEM) + c * MAXM;
    const float* pd = ws + WS_PD + c * TRI;
    const float* ns = ws + WS_NS;
    float lsum = 0.0f;
    for (int p = tid; p < P; p += 256) {
        int b = (int)((1.0f + sqrtf(1.0f + 8.0f * (float)p)) * 0.5f);
        while (b * (b - 1) / 2 > p) --b;
        while ((b + 1) * b / 2 <= p) ++b;
        const int a = p - b * (b - 1) / 2;
        const float dist = pd[b * (b - 1) / 2 + a];
        const int i = mem[a], j = mem[b];
        float J = __logf(ns[i] + ns[j]) + dist;
        float h = fmaxf(J, 0.0f);
        lsum += h * h;
    }
#pragma unroll
    for (int off = 32; off; off >>= 1) lsum += __shfl_xor(lsum, off, 64);
    const int wv = tid >> 6, lane = tid & 63;
    if (lane == 0) wsum[wv] = lsum;
    __syncthreads();
    if (tid == 0) {
        float s = wsum[0] + wsum[1] + wsum[2] + wsum[3];
        if (s != 0.0f) atomicAdd(&ws[WS_LOSS], s);
        __threadfence();
        unsigned d = atomicAdd((unsigned*)ws + WS_CTR, 1u);
        last = (d == NCLS - 1);
    }
    __syncthreads();
    if (last && tid < 64) {
        int mcv = ((const int*)(ws + WS_CNT))[tid];
        float lp = (float)(mcv * (mcv - 1));
#pragma unroll
        for (int off = 32; off; off >>= 1) lp += __shfl_down(lp, off, 64);
        if (tid == 0) {
            float total = atomicAdd(&ws[WS_LOSS], 0.0f);  // device-scope read
            out[0] = total / lp;
        }
    }
}

extern "C" void kernel_launch(void* const* d_in, const int* in_sizes, int n_in,
                              void* d_out, int out_size, void* d_ws, size_t ws_size,
                              hipStream_t stream) {
    const float* X  = (const float*)d_in[0];
    const int*  tgt = (const int*)d_in[1];
    float* ws  = (float*)d_ws;
    float* out = (float*)d_out;

    hipLaunchKernelGGL(prep_kernel, dim3(NN / 4), dim3(256), 0, stream, X, ws);
    hipLaunchKernelGGL(class_build_kernel, dim3(NN / 256), dim3(256), 0, stream, tgt, ws);
    hipLaunchKernelGGL(negsum_kernel, dim3(NBLK), dim3(256), 0, stream, tgt, ws);
    hipLaunchKernelGGL(pair2_kernel, dim3(NCLS), dim3(256), 0, stream, ws, out);
}

// Round 9
// 120.382 us; speedup vs baseline: 1.0343x; 1.0343x over previous
//
#include <hip/hip_runtime.h>
#include <math.h>

#define NN 4096
#define DD 512
#define MARGINF 1.0f
#define NCLS 64
#define MAXM 160
#define TRI (MAXM * (MAXM - 1) / 2)   // 12720
#define NBLK 2080                     // 64*65/2 triangular 64-tiles

typedef __attribute__((ext_vector_type(8))) short bf16x8;  // 8 bf16 (4 VGPRs)
typedef __attribute__((ext_vector_type(4))) float f32x4;   // 4 fp32 acc

// ws layout (float indices):
#define WS_SQ   0         // float[4096] ||x_i||^2
#define WS_NS   4096      // float[4096] neg_sum
#define WS_LOSS 8192      // float[1] sum hinge^2
#define WS_CTR  8193      // uint[1] pair2 completion counter
#define WS_CNT  8256      // int[64] class counts
#define WS_RK   8320      // int[4096] rank within class
#define WS_MEM  12416     // int[64*160] class member lists
#define WS_XF   32768     // ushort[4096*512] FRAGMENT-MAJOR bf16 X (4 MB)
                          //   Xf[((r16*16 + kb)*64 + lane)*8 + j]
                          //   r16=row>>4, kb=k>>5, lane=(k>>3&3)*16+(row&15), j=k&7
#define WS_PD   1081344   // float[64*TRI] positive-pair distances

__device__ __forceinline__ unsigned short f2bf(float f) {
    unsigned u = __float_as_uint(f);
    u += 0x7fffu + ((u >> 16) & 1u);   // round-to-nearest-even
    return (unsigned short)(u >> 16);
}

// Row norms + fragment-major bf16 conversion + zero-init. One wave per row.
// Lane covers k = lane*8 .. lane*8+7  (kb = lane>>2, q = lane&3).
__global__ __launch_bounds__(256) void prep_kernel(const float* __restrict__ X,
                                                   float* __restrict__ ws) {
    const int wv = threadIdx.x >> 6, lane = threadIdx.x & 63;
    const int row = blockIdx.x * 4 + wv;
    const float4* xr = (const float4*)(X + (size_t)row * DD);
    float4 a = xr[2 * lane], b = xr[2 * lane + 1];   // floats 8*lane .. 8*lane+7
    float s = a.x * a.x + a.y * a.y + a.z * a.z + a.w * a.w
            + b.x * b.x + b.y * b.y + b.z * b.z + b.w * b.w;
#pragma unroll
    for (int off = 32; off; off >>= 1) s += __shfl_down(s, off, 64);
    if (lane == 0) { ws[WS_SQ + row] = s; ws[WS_NS + row] = 0.0f; }
    ushort4 pa = {f2bf(a.x), f2bf(a.y), f2bf(a.z), f2bf(a.w)};
    ushort4 pb = {f2bf(b.x), f2bf(b.y), f2bf(b.z), f2bf(b.w)};
    const int r16 = row >> 4, m = row & 15;
    const int kb = lane >> 2, q = lane & 3;
    ushort4* dst = (ushort4*)((unsigned short*)(ws + WS_XF)
                              + ((size_t)(r16 * 16 + kb) * 64 + q * 16 + m) * 8);
    dst[0] = pa;
    dst[1] = pb;
    if (blockIdx.x == 0) {
        if (threadIdx.x < NCLS) ((int*)(ws + WS_CNT))[threadIdx.x] = 0;
        if (threadIdx.x == 0) { ws[WS_LOSS] = 0.0f; ((unsigned*)ws)[WS_CTR] = 0u; }
    }
}

__global__ __launch_bounds__(256) void class_build_kernel(const int* __restrict__ tgt,
                                                          float* __restrict__ ws) {
    const int t = blockIdx.x * 256 + threadIdx.x;
    const int c = tgt[t];
    int p = atomicAdd(&((int*)(ws + WS_CNT))[c], 1);
    ((int*)(ws + WS_RK))[t] = p;
    if (p < MAXM) ((int*)(ws + WS_MEM))[c * MAXM + p] = t;
}

// Gram via bf16 MFMA, fragment-major coalesced loads (no LDS/barriers)
// AND high occupancy: 64x64 tile per block, triangular grid of 2080
// blocks (8.1/CU -> 24-32 resident waves/CU vs R8's 8). Each wave: 32x32
// quadrant, 4x 1KB coalesced loads + 4 MFMA per K-iter, depth-1 prefetch.
__global__ __launch_bounds__(256, 6) void negsum_kernel(const int* __restrict__ tgt,
                                                        float* __restrict__ ws) {
    const int bidx = blockIdx.x;
    int bj = (int)((sqrtf(8.0f * (float)bidx + 1.0f) - 1.0f) * 0.5f);
    while (bj * (bj + 1) / 2 > bidx) --bj;
    while ((bj + 1) * (bj + 2) / 2 <= bidx) ++bj;
    const int bi = bidx - bj * (bj + 1) / 2;   // bi <= bj
    const int i0 = bi * 64, j0 = bj * 64;

    const int tid = threadIdx.x;
    const int w = tid >> 6, lane = tid & 63;
    const int m_ = lane & 15, q = lane >> 4;
    const int wr = (w & 1) * 32, wc = (w >> 1) * 32;
    const unsigned short* Xf = (const unsigned short*)(ws + WS_XF);

    // fragment (row-block rb, k-block it) at Xf + (rb*16 + it)*512 + lane*8
    const int air = (i0 + wr) >> 4;   // A row-blocks air, air+1
    const int bjr = (j0 + wc) >> 4;   // B row-blocks bjr, bjr+1
    const unsigned short* pA = Xf + (size_t)air * 8192 + lane * 8;
    const unsigned short* pB = Xf + (size_t)bjr * 8192 + lane * 8;

    f32x4 acc[2][2] = {};
    bf16x8 af[2], bfr[2], nA[2], nB[2];
#pragma unroll
    for (int u = 0; u < 2; ++u) {
        af[u]  = *(const bf16x8*)(pA + u * 8192);
        bfr[u] = *(const bf16x8*)(pB + u * 8192);
    }
#pragma unroll
    for (int it = 0; it < 16; ++it) {
        if (it < 15) {
#pragma unroll
            for (int u = 0; u < 2; ++u) {
                nA[u] = *(const bf16x8*)(pA + u * 8192 + (it + 1) * 512);
                nB[u] = *(const bf16x8*)(pB + u * 8192 + (it + 1) * 512);
            }
        }
        acc[0][0] = __builtin_amdgcn_mfma_f32_16x16x32_bf16(af[0], bfr[0], acc[0][0], 0, 0, 0);
        acc[0][1] = __builtin_amdgcn_mfma_f32_16x16x32_bf16(af[0], bfr[1], acc[0][1], 0, 0, 0);
        acc[1][0] = __builtin_amdgcn_mfma_f32_16x16x32_bf16(af[1], bfr[0], acc[1][0], 0, 0, 0);
        acc[1][1] = __builtin_amdgcn_mfma_f32_16x16x32_bf16(af[1], bfr[1], acc[1][1], 0, 0, 0);
#pragma unroll
        for (int u = 0; u < 2; ++u) { af[u] = nA[u]; bfr[u] = nB[u]; }
    }

    // epilogue: C/D map col=lane&15, row=(lane>>4)*4+reg
    const float* sq = ws + WS_SQ;
    float* ns = ws + WS_NS;
    const int* rk = (const int*)(ws + WS_RK);
    float* posd = ws + WS_PD;
    float sjv[2]; int tjv[2], jv[2];
#pragma unroll
    for (int v = 0; v < 2; ++v) {
        int j = j0 + wc + v * 16 + m_;
        jv[v] = j;
        sjv[v] = sq[j];
        tjv[v] = tgt[j];
    }
    float colp[2] = {0.0f, 0.0f};
#pragma unroll
    for (int u = 0; u < 2; ++u) {
#pragma unroll
        for (int r = 0; r < 4; ++r) {
            const int i = i0 + wr + u * 16 + q * 4 + r;
            const float si = sq[i];
            const int ti = tgt[i];
            float rp = 0.0f;
#pragma unroll
            for (int v = 0; v < 2; ++v) {
                float d2 = si + sjv[v] - 2.0f * acc[u][v][r];
                float dist = d2 > 0.0f ? sqrtf(d2) : 0.0f;
                if (tjv[v] != ti) {
                    float e = __expf(MARGINF - dist);
                    rp += e;
                    colp[v] += e;
                } else if (i < jv[v]) {
                    int ra = rk[i], rb = rk[jv[v]];
                    if (ra < MAXM && rb < MAXM) {
                        int hi = ra > rb ? ra : rb;
                        int lo = ra > rb ? rb : ra;
                        posd[ti * TRI + hi * (hi - 1) / 2 + lo] = dist;
                    }
                }
            }
            rp += __shfl_xor(rp, 1, 64);
            rp += __shfl_xor(rp, 2, 64);
            rp += __shfl_xor(rp, 4, 64);
            rp += __shfl_xor(rp, 8, 64);
            if (m_ == 0) atomicAdd(&ns[i], rp);
        }
    }
    if (bi != bj) {   // symmetric contribution: G[j][i] == G[i][j]
#pragma unroll
        for (int v = 0; v < 2; ++v) {
            float cp = colp[v];
            cp += __shfl_xor(cp, 16, 64);
            cp += __shfl_xor(cp, 32, 64);
            if (q == 0) atomicAdd(&ns[jv[v]], cp);
        }
    }
}

// Positive pairs from stored distances; last block computes the final mean.
__global__ __launch_bounds__(256) void pair2_kernel(float* __restrict__ ws,
                                                    float* __restrict__ out) {
    __shared__ float wsum[4];
    __shared__ bool last;
    const int c = blockIdx.x;
    const int tid = threadIdx.x;
    int mc = ((const int*)(ws + WS_CNT))[c];
    if (mc > MAXM) mc = MAXM;
    const int P = mc * (mc - 1) / 2;
    const int* mem = (const int*)(ws + WS_MEM) + c * MAXM;
    const float* pd = ws + WS_PD + c * TRI;
    const float* ns = ws + WS_NS;
    float lsum = 0.0f;
    for (int p = tid; p < P; p += 256) {
        int b = (int)((1.0f + sqrtf(1.0f + 8.0f * (float)p)) * 0.5f);
        while (b * (b - 1) / 2 > p) --b;
        while ((b + 1) * b / 2 <= p) ++b;
        const int a = p - b * (b - 1) / 2;
        const float dist = pd[b * (b - 1) / 2 + a];
        const int i = mem[a], j = mem[b];
        float J = __logf(ns[i] + ns[j]) + dist;
        float h = fmaxf(J, 0.0f);
        lsum += h * h;
    }
#pragma unroll
    for (int off = 32; off; off >>= 1) lsum += __shfl_xor(lsum, off, 64);
    const int wv = tid >> 6, lane = tid & 63;
    if (lane == 0) wsum[wv] = lsum;
    __syncthreads();
    if (tid == 0) {
        float s = wsum[0] + wsum[1] + wsum[2] + wsum[3];
        if (s != 0.0f) atomicAdd(&ws[WS_LOSS], s);
        __threadfence();
        unsigned d = atomicAdd((unsigned*)ws + WS_CTR, 1u);
        last = (d == NCLS - 1);
    }
    __syncthreads();
    if (last && tid < 64) {
        int mcv = ((const int*)(ws + WS_CNT))[tid];
        float lp = (float)(mcv * (mcv - 1));
#pragma unroll
        for (int off = 32; off; off >>= 1) lp += __shfl_down(lp, off, 64);
        if (tid == 0) {
            float total = atomicAdd(&ws[WS_LOSS], 0.0f);  // device-scope read
            out[0] = total / lp;
        }
    }
}

extern "C" void kernel_launch(void* const* d_in, const int* in_sizes, int n_in,
                              void* d_out, int out_size, void* d_ws, size_t ws_size,
                              hipStream_t stream) {
    const float* X  = (const float*)d_in[0];
    const int*  tgt = (const int*)d_in[1];
    float* ws  = (float*)d_ws;
    float* out = (float*)d_out;

    hipLaunchKernelGGL(prep_kernel, dim3(NN / 4), dim3(256), 0, stream, X, ws);
    hipLaunchKernelGGL(class_build_kernel, dim3(NN / 256), dim3(256), 0, stream, tgt, ws);
    hipLaunchKernelGGL(negsum_kernel, dim3(NBLK), dim3(256), 0, stream, tgt, ws);
    hipLaunchKernelGGL(pair2_kernel, dim3(NCLS), dim3(256), 0, stream, ws, out);
}

// Round 10
// 116.807 us; speedup vs baseline: 1.0659x; 1.0306x over previous
//
#include <hip/hip_runtime.h>
#include <math.h>

#define NN 4096
#define DD 512
#define MARGINF 1.0f
#define NCLS 64
#define MAXM 160
#define TRI (MAXM * (MAXM - 1) / 2)   // 12720
#define NBLK 2080                     // 64*65/2 triangular 64-tiles

typedef __attribute__((ext_vector_type(8))) short bf16x8;  // 8 bf16 (4 VGPRs)
typedef __attribute__((ext_vector_type(4))) float f32x4;   // 4 fp32 acc

// ws layout (float indices):
#define WS_SQ   0         // float[4096] ||x_i||^2
#define WS_NS   4096      // float[4096] neg_sum
#define WS_LOSS 8192      // float[1] sum hinge^2
#define WS_CTR  8193      // uint[1] pair2 completion counter
#define WS_LENP 8194      // float[1] sum over classes mc*(mc-1)
#define WS_RK   8320      // int[4096] rank within class (atomic-free)
#define WS_MEM  12416     // int[64*160] class member lists (rank-indexed)
#define WS_XF   32768     // ushort[4096*512] FRAGMENT-MAJOR bf16 X (4 MB)
                          //   Xf[((r16*16 + kb)*64 + (k>>3&3)*16 + (row&15))*8 + (k&7)]
#define WS_PD   1081344   // float[64*TRI] positive-pair distances

__device__ __forceinline__ unsigned short f2bf(float f) {
    unsigned u = __float_as_uint(f);
    u += 0x7fffu + ((u >> 16) & 1u);   // round-to-nearest-even
    return (unsigned short)(u >> 16);
}

// Row norms + fragment-major bf16 conversion + ATOMIC-FREE class ranks.
// rk[i] = #{j<i : tgt[j]==tgt[i]} via LDS scan; mem[c][rk]=i is race-free.
__global__ __launch_bounds__(256) void prep_kernel(const float* __restrict__ X,
                                                   const int* __restrict__ tgt,
                                                   float* __restrict__ ws) {
    __shared__ int tg[NN];   // 16 KB
    const int tid = threadIdx.x;
    for (int j = tid; j < NN; j += 256) tg[j] = tgt[j];

    const int wv = tid >> 6, lane = tid & 63;
    const int row = blockIdx.x * 4 + wv;
    const float4* xr = (const float4*)(X + (size_t)row * DD);
    float4 a = xr[2 * lane], b = xr[2 * lane + 1];   // floats 8*lane..8*lane+7
    float s = a.x * a.x + a.y * a.y + a.z * a.z + a.w * a.w
            + b.x * b.x + b.y * b.y + b.z * b.z + b.w * b.w;
#pragma unroll
    for (int off = 32; off; off >>= 1) s += __shfl_down(s, off, 64);

    ushort4 pa = {f2bf(a.x), f2bf(a.y), f2bf(a.z), f2bf(a.w)};
    ushort4 pb = {f2bf(b.x), f2bf(b.y), f2bf(b.z), f2bf(b.w)};
    const int r16 = row >> 4, m = row & 15;
    const int kb = lane >> 2, q = lane & 3;
    ushort4* dst = (ushort4*)((unsigned short*)(ws + WS_XF)
                              + ((size_t)(r16 * 16 + kb) * 64 + q * 16 + m) * 8);
    dst[0] = pa;
    dst[1] = pb;

    __syncthreads();
    const int myc = tg[row];
    int cnt = 0;
    for (int j = lane; j < row; j += 64) cnt += (tg[j] == myc) ? 1 : 0;
#pragma unroll
    for (int off = 32; off; off >>= 1) cnt += __shfl_down(cnt, off, 64);
    if (lane == 0) {
        ws[WS_SQ + row] = s;
        ws[WS_NS + row] = 0.0f;
        ((int*)(ws + WS_RK))[row] = cnt;
        if (cnt < MAXM) ((int*)(ws + WS_MEM))[myc * MAXM + cnt] = row;
    }
    if (blockIdx.x == 0 && tid == 0) {
        ws[WS_LOSS] = 0.0f;
        ((unsigned*)ws)[WS_CTR] = 0u;
        ws[WS_LENP] = 0.0f;
    }
}

// Gram via bf16 MFMA, fragment-major coalesced loads, 64x64 tile per block
// (triangular grid, 2080 blocks), DEPTH-2 prefetch ring: 16 outstanding 1KB
// loads/wave steady-state; iter t waits only on loads issued at t-2.
__global__ __launch_bounds__(256, 5) void negsum_kernel(const int* __restrict__ tgt,
                                                        float* __restrict__ ws) {
    const int bidx = blockIdx.x;
    int bj = (int)((sqrtf(8.0f * (float)bidx + 1.0f) - 1.0f) * 0.5f);
    while (bj * (bj + 1) / 2 > bidx) --bj;
    while ((bj + 1) * (bj + 2) / 2 <= bidx) ++bj;
    const int bi = bidx - bj * (bj + 1) / 2;   // bi <= bj
    const int i0 = bi * 64, j0 = bj * 64;

    const int tid = threadIdx.x;
    const int w = tid >> 6, lane = tid & 63;
    const int m_ = lane & 15, q = lane >> 4;
    const int wr = (w & 1) * 32, wc = (w >> 1) * 32;
    const unsigned short* Xf = (const unsigned short*)(ws + WS_XF);

    const int air = (i0 + wr) >> 4;
    const int bjr = (j0 + wc) >> 4;
    const unsigned short* pA = Xf + (size_t)air * 8192 + lane * 8;
    const unsigned short* pB = Xf + (size_t)bjr * 8192 + lane * 8;

    f32x4 acc[2][2] = {};
    bf16x8 rgA[3][2], rgB[3][2];
#pragma unroll
    for (int s = 0; s < 2; ++s)
#pragma unroll
        for (int u = 0; u < 2; ++u) {
            rgA[s][u] = *(const bf16x8*)(pA + u * 8192 + s * 512);
            rgB[s][u] = *(const bf16x8*)(pB + u * 8192 + s * 512);
        }
#pragma unroll
    for (int it = 0; it < 16; ++it) {
        const int cur = it % 3, nx = (it + 2) % 3;
        if (it < 14) {
#pragma unroll
            for (int u = 0; u < 2; ++u) {
                rgA[nx][u] = *(const bf16x8*)(pA + u * 8192 + (it + 2) * 512);
                rgB[nx][u] = *(const bf16x8*)(pB + u * 8192 + (it + 2) * 512);
            }
        }
        acc[0][0] = __builtin_amdgcn_mfma_f32_16x16x32_bf16(rgA[cur][0], rgB[cur][0], acc[0][0], 0, 0, 0);
        acc[0][1] = __builtin_amdgcn_mfma_f32_16x16x32_bf16(rgA[cur][0], rgB[cur][1], acc[0][1], 0, 0, 0);
        acc[1][0] = __builtin_amdgcn_mfma_f32_16x16x32_bf16(rgA[cur][1], rgB[cur][0], acc[1][0], 0, 0, 0);
        acc[1][1] = __builtin_amdgcn_mfma_f32_16x16x32_bf16(rgA[cur][1], rgB[cur][1], acc[1][1], 0, 0, 0);
    }

    // epilogue: C/D map col=lane&15, row=(lane>>4)*4+reg
    const float* sq = ws + WS_SQ;
    float* ns = ws + WS_NS;
    const int* rk = (const int*)(ws + WS_RK);
    float* posd = ws + WS_PD;
    float sjv[2]; int tjv[2], jv[2];
#pragma unroll
    for (int v = 0; v < 2; ++v) {
        int j = j0 + wc + v * 16 + m_;
        jv[v] = j;
        sjv[v] = sq[j];
        tjv[v] = tgt[j];
    }
    float colp[2] = {0.0f, 0.0f};
#pragma unroll
    for (int u = 0; u < 2; ++u) {
#pragma unroll
        for (int r = 0; r < 4; ++r) {
            const int i = i0 + wr + u * 16 + q * 4 + r;
            const float si = sq[i];
            const int ti = tgt[i];
            float rp = 0.0f;
#pragma unroll
            for (int v = 0; v < 2; ++v) {
                float d2 = si + sjv[v] - 2.0f * acc[u][v][r];
                float dist = d2 > 0.0f ? sqrtf(d2) : 0.0f;
                if (tjv[v] != ti) {
                    float e = __expf(MARGINF - dist);
                    rp += e;
                    colp[v] += e;
                } else if (i < jv[v]) {
                    int ra = rk[i], rb = rk[jv[v]];
                    if (ra < MAXM && rb < MAXM) {
                        int hi = ra > rb ? ra : rb;
                        int lo = ra > rb ? rb : ra;
                        posd[ti * TRI + hi * (hi - 1) / 2 + lo] = dist;
                    }
                }
            }
            rp += __shfl_xor(rp, 1, 64);
            rp += __shfl_xor(rp, 2, 64);
            rp += __shfl_xor(rp, 4, 64);
            rp += __shfl_xor(rp, 8, 64);
            if (m_ == 0) atomicAdd(&ns[i], rp);
        }
    }
    if (bi != bj) {   // symmetric contribution: G[j][i] == G[i][j]
#pragma unroll
        for (int v = 0; v < 2; ++v) {
            float cp = colp[v];
            cp += __shfl_xor(cp, 16, 64);
            cp += __shfl_xor(cp, 32, 64);
            if (q == 0) atomicAdd(&ns[jv[v]], cp);
        }
    }
}

// Positive pairs from stored distances; computes own class count (no
// class_build kernel); last block finalizes out = loss / len_p.
__global__ __launch_bounds__(256) void pair2_kernel(const int* __restrict__ tgt,
                                                    float* __restrict__ ws,
                                                    float* __restrict__ out) {
    __shared__ float wsum[4];
    __shared__ int csum[4];
    __shared__ bool last;
    const int c = blockIdx.x;
    const int tid = threadIdx.x;
    const int wv = tid >> 6, lane = tid & 63;

    int ccount = 0;
    for (int j = tid; j < NN; j += 256) ccount += (tgt[j] == c) ? 1 : 0;
#pragma unroll
    for (int off = 32; off; off >>= 1) ccount += __shfl_down(ccount, off, 64);
    if (lane == 0) csum[wv] = ccount;
    __syncthreads();
    int mc = csum[0] + csum[1] + csum[2] + csum[3];
    if (mc > MAXM) mc = MAXM;
    const int P = mc * (mc - 1) / 2;

    const int* mem = (const int*)(ws + WS_MEM) + c * MAXM;
    const float* pd = ws + WS_PD + c * TRI;
    const float* ns = ws + WS_NS;
    float lsum = 0.0f;
    for (int p = tid; p < P; p += 256) {
        int b = (int)((1.0f + sqrtf(1.0f + 8.0f * (float)p)) * 0.5f);
        while (b * (b - 1) / 2 > p) --b;
        while ((b + 1) * b / 2 <= p) ++b;
        const int a = p - b * (b - 1) / 2;
        const float dist = pd[b * (b - 1) / 2 + a];
        const int i = mem[a], j = mem[b];
        float J = __logf(ns[i] + ns[j]) + dist;
        float h = fmaxf(J, 0.0f);
        lsum += h * h;
    }
#pragma unroll
    for (int off = 32; off; off >>= 1) lsum += __shfl_xor(lsum, off, 64);
    if (lane == 0) wsum[wv] = lsum;
    __syncthreads();
    if (tid == 0) {
        float s = wsum[0] + wsum[1] + wsum[2] + wsum[3];
        if (s != 0.0f) atomicAdd(&ws[WS_LOSS], s);
        atomicAdd(&ws[WS_LENP], (float)(mc * (mc - 1)));
        __threadfence();
        unsigned d = atomicAdd((unsigned*)ws + WS_CTR, 1u);
        last = (d == NCLS - 1);
    }
    __syncthreads();
    if (last && tid == 0) {
        float total = atomicAdd(&ws[WS_LOSS], 0.0f);   // device-scope reads
        float lp = atomicAdd(&ws[WS_LENP], 0.0f);
        out[0] = total / lp;
    }
}

extern "C" void kernel_launch(void* const* d_in, const int* in_sizes, int n_in,
                              void* d_out, int out_size, void* d_ws, size_t ws_size,
                              hipStream_t stream) {
    const float* X  = (const float*)d_in[0];
    const int*  tgt = (const int*)d_in[1];
    float* ws  = (float*)d_ws;
    float* out = (float*)d_out;

    hipLaunchKernelGGL(prep_kernel, dim3(NN / 4), dim3(256), 0, stream, X, tgt, ws);
    hipLaunchKernelGGL(negsum_kernel, dim3(NBLK), dim3(256), 0, stream, tgt, ws);
    hipLaunchKernelGGL(pair2_kernel, dim3(NCLS), dim3(256), 0, stream, tgt, ws, out);
}